// Round 4
// baseline (2295.657 us; speedup 1.0000x reference)
//
#include <hip/hip_runtime.h>

// Problem constants (from reference): T=512, N=512, I=256, H=256
#define kT 512
#define kN 512
#define kH 256

typedef float  f32x4  __attribute__((ext_vector_type(4)));
typedef __bf16 bf16x8 __attribute__((ext_vector_type(8)));
typedef __bf16 bf16x4 __attribute__((ext_vector_type(4)));

static __device__ __forceinline__ float sigm(float x) {
  float e = __builtin_amdgcn_exp2f(-1.4426950408889634f * x);
  return __builtin_amdgcn_rcpf(1.0f + e);
}
static __device__ __forceinline__ float tanh_fast(float x) {
  float e = __builtin_amdgcn_exp2f(-2.8853900817779268f * x);
  return fmaf(2.0f, __builtin_amdgcn_rcpf(1.0f + e), -1.0f);
}

// ---------------------------------------------------------------------------
// Phase 1: gi = x @ W_ih^T + b_ih (+ b_hh for r,z), bf16.
// Global layout v2 (8B per lane, conflict-free scan ds_read_b64):
//   chunk(1024B) index = ((t*32 + sb)*8 + w2)*3 + gate
//   within chunk: [tp(2)][lane(64)][4 bf16]
//   value at (seq row s = lg*4+i, col j = gate*256 + w2*32 + tp*16 + c) = [tp][lane=lg*16+c][i]
// ---------------------------------------------------------------------------
__global__ __launch_bounds__(512) void gi_gemm(
    const float* __restrict__ x, const float* __restrict__ Wih,
    const float* __restrict__ bih, const float* __restrict__ bhh,
    __bf16* __restrict__ gis)
{
  __shared__ __align__(16) __bf16 Al[128][264];  // 256 k + 8 pad
  __shared__ __align__(16) __bf16 Bl[128][264];
  const int tid  = threadIdx.x;
  const int lane = tid & 63, w = tid >> 6;
  const int wm = w & 1, wn = w >> 1;            // 2 x 4 wave grid
  const int c = lane & 15, lg = lane >> 4;
  const long R0 = (long)blockIdx.x * 128;
  const int t  = (int)(R0 >> 9);
  const int n0 = (int)(R0 & 511);

  #pragma unroll
  for (int it = 0; it < 16; ++it) {
    int slot = tid + it * 512;
    int r  = slot >> 6;
    int kq = (slot & 63) * 4;
    float4 av = *(const float4*)(x + (R0 + r) * 256 + kq);
    bf16x4 a4 = {(__bf16)av.x, (__bf16)av.y, (__bf16)av.z, (__bf16)av.w};
    *(bf16x4*)(&Al[r][kq]) = a4;
  }

  for (int nb = 0; nb < 6; ++nb) {
    __syncthreads();
    #pragma unroll
    for (int it = 0; it < 16; ++it) {
      int slot = tid + it * 512;
      int r  = slot >> 6;
      int kq = (slot & 63) * 4;
      float4 bv = *(const float4*)(Wih + (long)(nb * 128 + r) * 256 + kq);
      bf16x4 b4 = {(__bf16)bv.x, (__bf16)bv.y, (__bf16)bv.z, (__bf16)bv.w};
      *(bf16x4*)(&Bl[r][kq]) = b4;
    }
    __syncthreads();

    const int gate = nb >> 1;
    f32x4 acc[4][2];
    #pragma unroll
    for (int nt = 0; nt < 2; ++nt) {
      int j = nb * 128 + wn * 32 + nt * 16 + c;
      float bv = bih[j] + (gate < 2 ? bhh[j] : 0.0f);
      #pragma unroll
      for (int mt = 0; mt < 4; ++mt) acc[mt][nt] = (f32x4){bv, bv, bv, bv};
    }

    #pragma unroll
    for (int ss = 0; ss < 8; ++ss) {
      bf16x8 af[4], bfr[2];
      #pragma unroll
      for (int mt = 0; mt < 4; ++mt)
        af[mt] = *(const bf16x8*)(&Al[wm * 64 + mt * 16 + c][ss * 32 + lg * 8]);
      #pragma unroll
      for (int nt = 0; nt < 2; ++nt)
        bfr[nt] = *(const bf16x8*)(&Bl[wn * 32 + nt * 16 + c][ss * 32 + lg * 8]);
      #pragma unroll
      for (int mt = 0; mt < 4; ++mt)
        #pragma unroll
        for (int nt = 0; nt < 2; ++nt)
          acc[mt][nt] = __builtin_amdgcn_mfma_f32_16x16x32_bf16(af[mt], bfr[nt], acc[mt][nt], 0, 0, 0);
    }

    // Epilogue v2: two 8B stores per mt (tp=0 / tp=1 halves of the chunk)
    const int w2g = (nb & 1) * 4 + wn;
    #pragma unroll
    for (int mt = 0; mt < 4; ++mt) {
      int sb = (n0 >> 4) + wm * 4 + mt;
      bf16x4 lo, hi;
      #pragma unroll
      for (int i = 0; i < 4; ++i) {
        lo[i] = (__bf16)acc[mt][0][i];
        hi[i] = (__bf16)acc[mt][1][i];
      }
      long chunk = (((long)(t * 32 + sb) * 8 + w2g) * 3 + gate);
      __bf16* p = gis + chunk * 512;
      *(bf16x4*)(p + lane * 4)       = lo;   // tp = 0
      *(bf16x4*)(p + 256 + lane * 4) = hi;   // tp = 1
    }
  }
}

// ---------------------------------------------------------------------------
// Phase 2: recurrent scan. 32 blocks x 1024 thr = 16 waves (4/SIMD, 128-reg
// budget by construction). Wave w owns h-columns [w*16, w*16+16) for ALL
// three gates: W-frags = 24 bf16x8 = 96 VGPR, gate math wave-local.
// h broadcast via 16KB XOR-swizzled double-buffered LDS; gi via 3-deep
// global_load_lds pipeline with counted vmcnt(7); done packed in LDS.
// ---------------------------------------------------------------------------
__global__ __launch_bounds__(1024) void gru_scan(
    const __bf16* __restrict__ gis, const float* __restrict__ h0,
    const float* __restrict__ done, const float* __restrict__ Whh,
    const float* __restrict__ bhh, float* __restrict__ out)
{
  __shared__ __align__(16) __bf16 hbuf[2][16 * 256];   // 16 KB
  __shared__ __align__(16) __bf16 gibuf[3][12288];     // 72 KB (24 KB / slot)
  __shared__ unsigned char doneL[kT * 16];             // 8 KB (row t = done[t+1])

  const int tid  = threadIdx.x;
  const int lane = tid & 63, w = tid >> 6;             // w = 0..15
  const int b  = blockIdx.x;
  const int nb = b * 16;
  const int c  = lane & 15, lg = lane >> 4;
  const int jh = w * 16 + c;                           // owned h column
  const int rx = (c & 7) << 4;                         // afr swizzle key

  // --- W_hh fragments -> 96 VGPRs (3 gate-tiles x 8 K-slices)
  bf16x8 wf[24];
  #pragma unroll
  for (int g = 0; g < 3; ++g) {
    const int j = g * 256 + jh;
    #pragma unroll
    for (int ss = 0; ss < 8; ++ss) {
      const int k0 = ss * 32 + lg * 8;
      float4 q0 = *(const float4*)(Whh + (long)j * 256 + k0);
      float4 q1 = *(const float4*)(Whh + (long)j * 256 + k0 + 4);
      bf16x8 v = {(__bf16)q0.x, (__bf16)q0.y, (__bf16)q0.z, (__bf16)q0.w,
                  (__bf16)q1.x, (__bf16)q1.y, (__bf16)q1.z, (__bf16)q1.w};
      wf[g * 8 + ss] = v;
    }
  }
  const float bn = bhh[512 + jh];

  // --- done -> LDS, shifted by 1 (row t holds done[t+1]; last row = 0)
  for (int idx = tid; idx < (kT - 1) * 16; idx += 1024) {
    int tt = idx >> 4, s = idx & 15;
    doneL[idx] = (unsigned char)(done[(long)(tt + 1) * kN + nb + s] != 0.0f);
  }
  if (tid < 16) doneL[(kT - 1) * 16 + tid] = 0;

  // --- init h (scaled by 1-done[0]) into hbuf[0] + per-lane h_old
  {
    const int s  = tid >> 6;            // 0..15
    const int k4 = (tid & 63) * 4;      // 0..252
    float sc = 1.0f - done[nb + s];
    const float* hp = h0 + (long)(nb + s) * 256 + k4;
    bf16x4 v = {(__bf16)(hp[0] * sc), (__bf16)(hp[1] * sc),
                (__bf16)(hp[2] * sc), (__bf16)(hp[3] * sc)};
    int colb = (k4 * 2) ^ ((s & 7) << 4);
    *(bf16x4*)(&hbuf[0][s * 256 + (colb >> 1)]) = v;
  }
  float hold[4];
  #pragma unroll
  for (int i = 0; i < 4; ++i) {
    int s = lg * 4 + i;
    hold[i] = h0[(long)(nb + s) * 256 + jh] * (1.0f - done[nb + s]);
  }

  // --- prologue: DMA gi for t=0,1 (waves 0..7), drain L(0), barrier
  if (w < 8) {
    #pragma unroll
    for (int tt = 0; tt < 2; ++tt) {
      #pragma unroll
      for (int g = 0; g < 3; ++g) {
        const __bf16* src = gis + ((((long)tt * 32 + b) * 8 + w) * 3 + g) * 512 + lane * 8;
        __builtin_amdgcn_global_load_lds(
            (const __attribute__((address_space(1))) unsigned int*)src,
            (__attribute__((address_space(3))) unsigned int*)(&gibuf[tt][w * 1536 + g * 512 + lane * 8]),
            16, 0, 0);
      }
    }
  }
  asm volatile("s_waitcnt vmcnt(3)" ::: "memory");
  asm volatile("s_waitcnt lgkmcnt(0)" ::: "memory");
  asm volatile("s_barrier" ::: "memory");

  int slot = 0;        // t % 3
  #pragma unroll 1
  for (int t = 0; t < kT; ++t) {
    // gi + done for this step (conflict-free b64 reads)
    const __bf16* gb = &gibuf[slot][(w >> 1) * 1536 + (w & 1) * 256 + lane * 4];
    bf16x4 q0 = *(const bf16x4*)(gb);
    bf16x4 q1 = *(const bf16x4*)(gb + 512);
    bf16x4 qn = *(const bf16x4*)(gb + 1024);
    unsigned du = *(const unsigned*)(&doneL[t * 16 + lg * 4]);

    f32x4 acc0, acc1, acc2;
    #pragma unroll
    for (int i = 0; i < 4; ++i) { acc0[i] = (float)q0[i]; acc1[i] = (float)q1[i]; }
    acc2 = (f32x4){bn, bn, bn, bn};

    // MFMA over K=256: A = h from swizzled LDS, B = W from registers
    const __bf16* hb = &hbuf[t & 1][0];
    #pragma unroll
    for (int ss = 0; ss < 8; ++ss) {
      int colb = (ss * 64 + lg * 16) ^ rx;
      bf16x8 afr = *(const bf16x8*)(&hb[c * 256 + (colb >> 1)]);
      acc0 = __builtin_amdgcn_mfma_f32_16x16x32_bf16(afr, wf[ss],      acc0, 0, 0, 0);
      acc1 = __builtin_amdgcn_mfma_f32_16x16x32_bf16(afr, wf[8 + ss],  acc1, 0, 0, 0);
      acc2 = __builtin_amdgcn_mfma_f32_16x16x32_bf16(afr, wf[16 + ss], acc2, 0, 0, 0);
    }

    // DMA gi(t+2) (waves 0..7; wave-uniform branch)
    if (w < 8 && t < kT - 2) {
      int ns = slot + 2; if (ns >= 3) ns -= 3;
      const __bf16* src = gis + ((((long)(t + 2) * 32 + b) * 8 + w) * 3) * 512 + lane * 8;
      #pragma unroll
      for (int g = 0; g < 3; ++g)
        __builtin_amdgcn_global_load_lds(
            (const __attribute__((address_space(1))) unsigned int*)(src + g * 512),
            (__attribute__((address_space(3))) unsigned int*)(&gibuf[ns][w * 1536 + g * 512 + lane * 8]),
            16, 0, 0);
    }

    // gates + state update + stores (4 outputs/thread, all same column jh)
    float* op = out + ((long)t * kN + nb) * kH + jh;
    __bf16* hw = &hbuf[(t & 1) ^ 1][0];
    #pragma unroll
    for (int i = 0; i < 4; ++i) {
      const int s = lg * 4 + i;
      const float dn = (float)((du >> (8 * i)) & 255u);
      float r  = sigm(acc0[i]);
      float z  = sigm(acc1[i]);
      float npv = (float)qn[i] + r * acc2[i];
      float n  = tanh_fast(npv);
      float hn = n + z * (hold[i] - n);
      op[(long)s * kH] = hn;
      float hk = hn * (1.0f - dn);
      hold[i] = hk;
      int colb = (jh * 2) ^ ((s & 7) << 4);
      hw[s * 256 + (colb >> 1)] = (__bf16)hk;
    }

    // h(t+1) visible; keep gi DMAs in flight across the barrier.
    // vmcnt(7): at most {4 stores(t) + 3 loads(t+2)} may remain -> L(t+1) landed.
    asm volatile("s_waitcnt lgkmcnt(0)" ::: "memory");
    asm volatile("s_waitcnt vmcnt(7)" ::: "memory");
    asm volatile("s_barrier" ::: "memory");

    slot = (slot == 2) ? 0 : slot + 1;
  }

  // final hidden state (doneL last row = 0, so hold == h_T)
  float* outF = out + (long)kT * kN * kH;
  #pragma unroll
  for (int i = 0; i < 4; ++i)
    outF[(long)(nb + lg * 4 + i) * kH + jh] = hold[i];
}

// ---------------------------------------------------------------------------
// Fallback (only if ws too small for gi): naive fp32, correct but slow.
// ---------------------------------------------------------------------------
__global__ __launch_bounds__(256) void gru_naive(
    const float* __restrict__ x, const float* __restrict__ h0,
    const float* __restrict__ done, const float* __restrict__ Wih,
    const float* __restrict__ Whh, const float* __restrict__ bih,
    const float* __restrict__ bhh, float* __restrict__ out)
{
  __shared__ float hsA[16][257];
  __shared__ float hsB[16][257];
  const int tid = threadIdx.x;
  const int b = blockIdx.x, nb = b * 16;
  for (int s = 0; s < 16; ++s)
    hsA[s][tid] = h0[(long)(nb + s) * 256 + tid] * (1.0f - done[nb + s]);
  __syncthreads();
  float (*hr)[257] = hsA;
  float (*hw)[257] = hsB;
  float* outF = out + (long)kT * kN * kH;
  for (int t = 0; t < kT; ++t) {
    for (int s = 0; s < 16; ++s) {
      const float* xr = x + ((long)t * kN + nb + s) * 256;
      float pr  = bih[tid] + bhh[tid];
      float pz  = bih[256 + tid] + bhh[256 + tid];
      float pnx = bih[512 + tid];
      float pnh = bhh[512 + tid];
      const float* wr = Wih + (long)tid * 256;
      const float* wz = Wih + (long)(256 + tid) * 256;
      const float* wn = Wih + (long)(512 + tid) * 256;
      const float* vr = Whh + (long)tid * 256;
      const float* vz = Whh + (long)(256 + tid) * 256;
      const float* vn = Whh + (long)(512 + tid) * 256;
      #pragma unroll 4
      for (int k = 0; k < 256; ++k) {
        float xv = xr[k], hv = hr[s][k];
        pr  = fmaf(xv, wr[k], pr);  pr  = fmaf(hv, vr[k], pr);
        pz  = fmaf(xv, wz[k], pz);  pz  = fmaf(hv, vz[k], pz);
        pnx = fmaf(xv, wn[k], pnx); pnh = fmaf(hv, vn[k], pnh);
      }
      float r = sigm(pr), z = sigm(pz);
      float n = tanh_fast(pnx + r * pnh);
      float ho = hr[s][tid];
      float hn = n + z * (ho - n);
      out[((long)t * kN + nb + s) * 256 + tid] = hn;
      if (t == kT - 1) outF[(long)(nb + s) * 256 + tid] = hn;
      float d = (t < kT - 1) ? done[(long)(t + 1) * kN + nb + s] : 0.0f;
      hw[s][tid] = hn * (1.0f - d);
    }
    __syncthreads();
    float (*tmp)[257] = hr; hr = hw; hw = tmp;
  }
}

extern "C" void kernel_launch(void* const* d_in, const int* in_sizes, int n_in,
                              void* d_out, int out_size, void* d_ws, size_t ws_size,
                              hipStream_t stream) {
  const float* x    = (const float*)d_in[0];
  const float* h0   = (const float*)d_in[1];
  const float* done = (const float*)d_in[2];
  const float* Wih  = (const float*)d_in[3];
  const float* Whh  = (const float*)d_in[4];
  const float* bih  = (const float*)d_in[5];
  const float* bhh  = (const float*)d_in[6];
  float* out = (float*)d_out;

  const size_t GI_BYTES = (size_t)kT * kN * 768 * 2;  // 402.7 MB bf16
  if (ws_size >= GI_BYTES) {
    __bf16* gis = (__bf16*)d_ws;
    hipLaunchKernelGGL(gi_gemm, dim3(2048), dim3(512), 0, stream, x, Wih, bih, bhh, gis);
    hipLaunchKernelGGL(gru_scan, dim3(32), dim3(1024), 0, stream, gis, h0, done, Whh, bhh, out);
  } else {
    hipLaunchKernelGGL(gru_naive, dim3(32), dim3(256), 0, stream, x, h0, done, Wih, Whh, bih, bhh, out);
  }
}